// Round 11
// baseline (28.862 us; speedup 1.0000x reference)
//
#include <hip/hip_runtime.h>
#include <hip/hip_bf16.h>
#include <utility>

typedef __fp16 h2    __attribute__((ext_vector_type(2)));
typedef __fp16 v8h   __attribute__((ext_vector_type(8)));
typedef _Float16 v8f16 __attribute__((ext_vector_type(8)));
typedef float  v2f   __attribute__((ext_vector_type(2)));
typedef float  v4f   __attribute__((ext_vector_type(4)));
typedef float  v16f  __attribute__((ext_vector_type(16)));

#define NT 5                      // n-tiles (160 cols: 136 real + 24 pad)
#define KTSTRIDE (NT * 64 * 8)    // shorts per kt slice = 2560
#define NCHUNK (12 * NT * 64)     // 16B chunks in U = 3840

__device__ __forceinline__ short h16(float f) {
    return __builtin_bit_cast(short, (_Float16)f);   // RNE f32->f16
}

__device__ __forceinline__ void gload16(const short* g, short* l) {
    __builtin_amdgcn_global_load_lds(
        (const __attribute__((address_space(1))) unsigned int*)g,
        (__attribute__((address_space(3))) unsigned int*)l, 16, 0, 0);
}

__device__ __forceinline__ v8h pack4(h2 a, h2 b, h2 c, h2 d) {
    union { int4 i; v8h h; } u;
    u.i = make_int4(__builtin_bit_cast(int, a), __builtin_bit_cast(int, b),
                    __builtin_bit_cast(int, c), __builtin_bit_cast(int, d));
    return u.h;
}

__device__ __forceinline__ v16f mfma_f16(v8h a, v8h b, v16f c) {
    return __builtin_amdgcn_mfma_f32_32x32x16_f16(
        __builtin_bit_cast(v8f16, a), __builtin_bit_cast(v8f16, b), c, 0, 0, 0);
}

// tri-pack mapping: col n (0..135) <-> (p<=q)
constexpr int pof(int n) {
    int p = 0, b = 0;
    while (b + (16 - p) <= n) { b += 16 - p; ++p; }
    return p;
}
constexpr int qof(int n) {
    int p = 0, b = 0;
    while (b + (16 - p) <= n) { b += 16 - p; ++p; }
    return p + (n - b);
}

// compile-time component extract from 4x v4f (registers, no dynamic index)
template<int I>
__device__ __forceinline__ float xi(v4f f0, v4f f1, v4f f2, v4f f3) {
    if constexpr (I < 4)       return f0[I];
    else if constexpr (I < 8)  return f1[I - 4];
    else if constexpr (I < 12) return f2[I - 8];
    else                       return f3[I - 12];
}

// one packed pair: s2 += {a[rgp],a[rgp+1]} * {xp*xq, xp'*xq'}   (pk_mul+pk_fma)
template<int NTI, int H, int R2>
__device__ __forceinline__ void pair2(v2f& s2, const v16f& a,
                                      v4f f0, v4f f1, v4f f2, v4f f3) {
    constexpr int rgp = 2 * R2;
    constexpr int N0 = NTI * 32 + (rgp & 3) + 8 * (rgp >> 2) + 4 * H;
    if constexpr (N0 < 136) {
        v2f xp2, xq2, a2;
        xp2[0] = xi<pof(N0)>(f0, f1, f2, f3);
        xq2[0] = xi<qof(N0)>(f0, f1, f2, f3);
        if constexpr (N0 + 1 < 136) {
            xp2[1] = xi<pof(N0 + 1)>(f0, f1, f2, f3);
            xq2[1] = xi<qof(N0 + 1)>(f0, f1, f2, f3);
        } else { xp2[1] = 0.f; xq2[1] = 0.f; }
        a2[0] = a[rgp]; a2[1] = a[rgp + 1];
        s2 += a2 * (xp2 * xq2);
    }
}

template<int NTI, int H, int... R2>
__device__ __forceinline__ void epi2_impl(v2f& s2, const v16f& a, v4f f0, v4f f1,
                                          v4f f2, v4f f3,
                                          std::integer_sequence<int, R2...>) {
    ((pair2<NTI, H, R2>(s2, a, f0, f1, f2, f3)), ...);
}
template<int NTI, int H>
__device__ __forceinline__ void epi2(v2f& s2, const v16f& a, v4f f0, v4f f1,
                                     v4f f2, v4f f3) {
    epi2_impl<NTI, H>(s2, a, f0, f1, f2, f3, std::make_integer_sequence<int, 8>{});
}

// ---------------------------------------------------------------------------
// Prep: (a) symmetrized U3/U2 -> fragment-ordered fp16 A-matrix (tri-packed),
// (b) per-node species e[node] (argmax of y).
// ---------------------------------------------------------------------------
__global__ void symcon_prep(const float* __restrict__ U3, const float* __restrict__ U2,
                            const float* __restrict__ y, short* __restrict__ Bg)
{
    const int g = blockIdx.x * 256 + threadIdx.x;   // 0..4607
    if (g < 2560) {
        const int n = g >> 4;                       // column 0..159
        const int i = g & 15;
        const int nt = n >> 5, lb = n & 31;
        const int lane = lb | ((i >> 3) << 5), j = i & 7;
        short* dst = Bg + (nt * 64 + lane) * 8 + j;
        if (n < 136) {
            int p = 0, base = 0;
            while (base + (16 - p) <= n) { base += 16 - p; ++p; }
            const int q = p + (n - base);
            const float* up = U3 + ((p * 16 + q) * 16 + i) * 11;
            const float* uq = U3 + ((q * 16 + p) * 16 + i) * 11;
            #pragma unroll
            for (int k3 = 0; k3 < 11; ++k3)
                dst[k3 * KTSTRIDE] = h16(up[k3] + (p != q ? uq[k3] : 0.f));
            if (i == 0) {
                short* d0 = Bg + 11 * KTSTRIDE + (nt * 64 + lb) * 8;
                #pragma unroll
                for (int jj = 0; jj < 4; ++jj)
                    d0[jj] = h16(U2[(p * 16 + q) * 4 + jj] + (p != q ? U2[(q * 16 + p) * 4 + jj] : 0.f));
                #pragma unroll
                for (int jj = 4; jj < 8; ++jj) d0[jj] = 0;
                short* d1 = Bg + 11 * KTSTRIDE + (nt * 64 + lb + 32) * 8;
                #pragma unroll
                for (int jj = 0; jj < 8; ++jj) d1[jj] = 0;
            }
        } else {
            #pragma unroll
            for (int k3 = 0; k3 < 11; ++k3) dst[k3 * KTSTRIDE] = 0;
            if (i == 0) {
                short* d0 = Bg + 11 * KTSTRIDE + (nt * 64 + lb) * 8;
                short* d1 = Bg + 11 * KTSTRIDE + (nt * 64 + lb + 32) * 8;
                #pragma unroll
                for (int jj = 0; jj < 8; ++jj) { d0[jj] = 0; d1[jj] = 0; }
            }
        }
    } else if (g < 2560 + 2048) {
        const int node = g - 2560;
        const float* yr = y + node * 10;
        int e = 0; float best = yr[0];
        #pragma unroll
        for (int s2 = 1; s2 < 10; ++s2) { const float v = yr[s2]; if (v > best) { best = v; e = s2; } }
        ((int*)(Bg + 12 * KTSTRIDE))[node] = e;
    }
}

// ---------------------------------------------------------------------------
// Main: 512-thread block = 8 waves = (2 nodes x 4 ch-groups) per job; U (60 KB)
// staged once to LDS, ONE barrier, then 2 jobs (node-pairs) free-running.
// K-loop: 5 ds_read_b128 + in-reg fp16 B build + setprio'd 5-MFMA cluster.
// Epilogue: packed-f32 (v_pk_mul/fma), pad-skipped, register-only.
// ---------------------------------------------------------------------------
__global__ __launch_bounds__(512, 4)
void symcon_main(const float* __restrict__ x,
                 const float* __restrict__ U1, const float* __restrict__ W3,
                 const float* __restrict__ W2, const float* __restrict__ W1,
                 const short* __restrict__ Bg, float* __restrict__ out)
{
    __shared__ __align__(16) short Ul[NCHUNK * 8];   // 61440 B

    const int tid  = threadIdx.x;
    const int lane = tid & 63;
    const int wid  = tid >> 6;            // 0..7
    const int col  = lane & 31;
    const int h    = lane >> 5;
    const int wr   = wid & 3;
    const int m    = wr * 32 + col;       // channel this lane owns
    const int* eA  = (const int*)(Bg + 12 * KTSTRIDE);

    // ---- stage U into LDS: 3840 chunks = 60 wave-loads ----
    #pragma unroll
    for (int jj = 0; jj < 7; ++jj) {
        const int c = ((jj * 8 + wid) << 6) + lane;
        gload16(Bg + c * 8, &Ul[c * 8]);
    }
    if (wid < 4) {
        const int c = ((56 + wid) << 6) + lane;
        gload16(Bg + c * 8, &Ul[c * 8]);
    }

    __syncthreads();   // U staged (drains vmcnt); the ONLY barrier

    const short* Up = Ul + lane * 8;

    #pragma unroll
    for (int j = 0; j < 2; ++j) {
        const int node = (blockIdx.x * 2 + j) * 2 + (wid >> 2);
        const int e    = eA[node];

        // ---- lane's x half (i = 8h..8h+7) -> packed fp16 ----
        const float* xp = x + ((size_t)node * 128 + m) * 16;
        h2 xh[4];
        {
            const v4f lo = *reinterpret_cast<const v4f*>(xp + h * 8);
            const v4f hi = *reinterpret_cast<const v4f*>(xp + h * 8 + 4);
            xh[0] = h2{(__fp16)lo[0], (__fp16)lo[1]};
            xh[1] = h2{(__fp16)lo[2], (__fp16)lo[3]};
            xh[2] = h2{(__fp16)hi[0], (__fp16)hi[1]};
            xh[3] = h2{(__fp16)hi[2], (__fp16)hi[3]};
        }

        // ---- per-lane weights ----
        float w3r[11], w2r[4];
        #pragma unroll
        for (int k = 0; k < 11; ++k) w3r[k] = W3[(e * 11 + k) * 128 + m];
        #pragma unroll
        for (int k = 0; k < 4; ++k)  w2r[k] = W2[(e * 4 + k) * 128 + m];
        const float w1v = W1[e * 128 + m];

        v16f a0 = {}, a1 = {}, a2 = {}, a3 = {}, a4 = {};

        // ---- K loop: 12 kt x 5 n-tiles; A from LDS, B built in-register ----
        #pragma unroll
        for (int kt = 0; kt < 12; ++kt) {
            const v8h u0 = *reinterpret_cast<const v8h*>(Up + (kt * NT + 0) * 512);
            const v8h u1 = *reinterpret_cast<const v8h*>(Up + (kt * NT + 1) * 512);
            const v8h u2 = *reinterpret_cast<const v8h*>(Up + (kt * NT + 2) * 512);
            const v8h u3 = *reinterpret_cast<const v8h*>(Up + (kt * NT + 3) * 512);
            const v8h u4 = *reinterpret_cast<const v8h*>(Up + (kt * NT + 4) * 512);
            v8h b;
            if (kt < 11) {
                const __fp16 w = (__fp16)w3r[kt];
                const h2 wh = h2{w, w};
                b = pack4(xh[0] * wh, xh[1] * wh, xh[2] * wh, xh[3] * wh);
            } else {
                const h2 z = {};
                const h2 p0 = h ? z : h2{(__fp16)w2r[0], (__fp16)w2r[1]};
                const h2 p1 = h ? z : h2{(__fp16)w2r[2], (__fp16)w2r[3]};
                b = pack4(p0, p1, z, z);
            }
            __builtin_amdgcn_s_setprio(1);
            a0 = mfma_f16(u0, b, a0);
            a1 = mfma_f16(u1, b, a1);
            a2 = mfma_f16(u2, b, a2);
            a3 = mfma_f16(u3, b, a3);
            a4 = mfma_f16(u4, b, a4);
            __builtin_amdgcn_s_setprio(0);
        }

        // ---- reload full x row, packed-f32 epilogue + U1 term ----
        const v4f f0 = *reinterpret_cast<const v4f*>(xp);
        const v4f f1 = *reinterpret_cast<const v4f*>(xp + 4);
        const v4f f2 = *reinterpret_cast<const v4f*>(xp + 8);
        const v4f f3 = *reinterpret_cast<const v4f*>(xp + 12);

        v2f s2 = {0.f, 0.f};
        if (h == 0) {
            epi2<0, 0>(s2, a0, f0, f1, f2, f3);
            epi2<1, 0>(s2, a1, f0, f1, f2, f3);
            epi2<2, 0>(s2, a2, f0, f1, f2, f3);
            epi2<3, 0>(s2, a3, f0, f1, f2, f3);
            epi2<4, 0>(s2, a4, f0, f1, f2, f3);
        } else {
            epi2<0, 1>(s2, a0, f0, f1, f2, f3);
            epi2<1, 1>(s2, a1, f0, f1, f2, f3);
            epi2<2, 1>(s2, a2, f0, f1, f2, f3);
            epi2<3, 1>(s2, a3, f0, f1, f2, f3);
            epi2<4, 1>(s2, a4, f0, f1, f2, f3);
        }
        float s = s2[0] + s2[1];

        float u1dot;
        {
            const v4f u0q = *reinterpret_cast<const v4f*>(U1);
            const v4f u1q = *reinterpret_cast<const v4f*>(U1 + 4);
            const v4f u2q = *reinterpret_cast<const v4f*>(U1 + 8);
            const v4f u3q = *reinterpret_cast<const v4f*>(U1 + 12);
            const v4f d = f0 * u0q + f1 * u1q + f2 * u2q + f3 * u3q;
            u1dot = d[0] + d[1] + d[2] + d[3];
        }

        s += __shfl_xor(s, 32);   // combine h=0/h=1 n-halves (same m)

        if (h == 0)
            out[(size_t)node * 128 + m] = s + w1v * u1dot;
    }
}

extern "C" void kernel_launch(void* const* d_in, const int* in_sizes, int n_in,
                              void* d_out, int out_size, void* d_ws, size_t ws_size,
                              hipStream_t stream) {
    const float* x  = (const float*)d_in[0];
    const float* y  = (const float*)d_in[1];
    const float* U3 = (const float*)d_in[2];
    const float* U2 = (const float*)d_in[3];
    const float* U1 = (const float*)d_in[4];
    const float* W3 = (const float*)d_in[5];
    const float* W2 = (const float*)d_in[6];
    const float* W1 = (const float*)d_in[7];
    short* Bg = (short*)d_ws;   // 60 KB fp16 Usym + 8 KB e[]

    symcon_prep<<<18, 256, 0, stream>>>(U3, U2, y, Bg);
    symcon_main<<<512, 512, 0, stream>>>(x, U1, W3, W2, W1, Bg, (float*)d_out);
}

// Round 12
// 27.527 us; speedup vs baseline: 1.0485x; 1.0485x over previous
//
#include <hip/hip_runtime.h>
#include <hip/hip_bf16.h>
#include <utility>

typedef __fp16 h2    __attribute__((ext_vector_type(2)));
typedef __fp16 v8h   __attribute__((ext_vector_type(8)));
typedef _Float16 v8f16 __attribute__((ext_vector_type(8)));
typedef float  v2f   __attribute__((ext_vector_type(2)));
typedef float  v4f   __attribute__((ext_vector_type(4)));
typedef float  v16f  __attribute__((ext_vector_type(16)));

#define NT 5                      // n-tiles (160 cols: 136 real + 24 pad)
#define KTSTRIDE (NT * 64 * 8)    // shorts per kt slice = 2560
#define NCHUNK (12 * NT * 64)     // 16B chunks in U = 3840

__device__ __forceinline__ short h16(float f) {
    return __builtin_bit_cast(short, (_Float16)f);   // RNE f32->f16
}

__device__ __forceinline__ void gload16(const short* g, short* l) {
    __builtin_amdgcn_global_load_lds(
        (const __attribute__((address_space(1))) unsigned int*)g,
        (__attribute__((address_space(3))) unsigned int*)l, 16, 0, 0);
}

__device__ __forceinline__ v8h pack4(h2 a, h2 b, h2 c, h2 d) {
    union { int4 i; v8h h; } u;
    u.i = make_int4(__builtin_bit_cast(int, a), __builtin_bit_cast(int, b),
                    __builtin_bit_cast(int, c), __builtin_bit_cast(int, d));
    return u.h;
}

__device__ __forceinline__ v16f mfma_f16(v8h a, v8h b, v16f c) {
    return __builtin_amdgcn_mfma_f32_32x32x16_f16(
        __builtin_bit_cast(v8f16, a), __builtin_bit_cast(v8f16, b), c, 0, 0, 0);
}

// tri-pack mapping: col n (0..135) <-> (p<=q)
constexpr int pof(int n) {
    int p = 0, b = 0;
    while (b + (16 - p) <= n) { b += 16 - p; ++p; }
    return p;
}
constexpr int qof(int n) {
    int p = 0, b = 0;
    while (b + (16 - p) <= n) { b += 16 - p; ++p; }
    return p + (n - b);
}

// compile-time component extract from 4x v4f (registers, no dynamic index)
template<int I>
__device__ __forceinline__ float xi(v4f f0, v4f f1, v4f f2, v4f f3) {
    if constexpr (I < 4)       return f0[I];
    else if constexpr (I < 8)  return f1[I - 4];
    else if constexpr (I < 12) return f2[I - 8];
    else                       return f3[I - 12];
}

// one packed pair: s2 += {a[rgp],a[rgp+1]} * {xp*xq, xp'*xq'}  (v_pk_mul+v_pk_fma)
template<int NTI, int H, int R2>
__device__ __forceinline__ void pair2(v2f& s2, const v16f& a,
                                      v4f f0, v4f f1, v4f f2, v4f f3) {
    constexpr int rgp = 2 * R2;
    constexpr int N0 = NTI * 32 + (rgp & 3) + 8 * (rgp >> 2) + 4 * H;
    if constexpr (N0 < 136) {
        v2f xp2, xq2, a2;
        xp2[0] = xi<pof(N0)>(f0, f1, f2, f3);
        xq2[0] = xi<qof(N0)>(f0, f1, f2, f3);
        if constexpr (N0 + 1 < 136) {
            xp2[1] = xi<pof(N0 + 1)>(f0, f1, f2, f3);
            xq2[1] = xi<qof(N0 + 1)>(f0, f1, f2, f3);
        } else { xp2[1] = 0.f; xq2[1] = 0.f; }
        a2[0] = a[rgp]; a2[1] = a[rgp + 1];
        s2 += a2 * (xp2 * xq2);
    }
}

template<int NTI, int H, int... R2>
__device__ __forceinline__ void epi2_impl(v2f& s2, const v16f& a, v4f f0, v4f f1,
                                          v4f f2, v4f f3,
                                          std::integer_sequence<int, R2...>) {
    ((pair2<NTI, H, R2>(s2, a, f0, f1, f2, f3)), ...);
}
template<int NTI, int H>
__device__ __forceinline__ void epi2(v2f& s2, const v16f& a, v4f f0, v4f f1,
                                     v4f f2, v4f f3) {
    epi2_impl<NTI, H>(s2, a, f0, f1, f2, f3, std::make_integer_sequence<int, 8>{});
}

// ---------------------------------------------------------------------------
// Prep: (a) symmetrized U3/U2 -> fragment-ordered fp16 A-matrix (tri-packed),
// (b) per-node species e[node] (argmax of y), stored after U.
// ---------------------------------------------------------------------------
__global__ void symcon_prep(const float* __restrict__ U3, const float* __restrict__ U2,
                            const float* __restrict__ y, short* __restrict__ Bg)
{
    const int g = blockIdx.x * 256 + threadIdx.x;   // 0..4607
    if (g < 2560) {
        const int n = g >> 4;                       // column 0..159
        const int i = g & 15;
        const int nt = n >> 5, lb = n & 31;
        const int lane = lb | ((i >> 3) << 5), j = i & 7;
        short* dst = Bg + (nt * 64 + lane) * 8 + j;
        if (n < 136) {
            int p = 0, base = 0;
            while (base + (16 - p) <= n) { base += 16 - p; ++p; }
            const int q = p + (n - base);
            const float* up = U3 + ((p * 16 + q) * 16 + i) * 11;
            const float* uq = U3 + ((q * 16 + p) * 16 + i) * 11;
            #pragma unroll
            for (int k3 = 0; k3 < 11; ++k3)
                dst[k3 * KTSTRIDE] = h16(up[k3] + (p != q ? uq[k3] : 0.f));
            if (i == 0) {
                short* d0 = Bg + 11 * KTSTRIDE + (nt * 64 + lb) * 8;
                #pragma unroll
                for (int jj = 0; jj < 4; ++jj)
                    d0[jj] = h16(U2[(p * 16 + q) * 4 + jj] + (p != q ? U2[(q * 16 + p) * 4 + jj] : 0.f));
                #pragma unroll
                for (int jj = 4; jj < 8; ++jj) d0[jj] = 0;
                short* d1 = Bg + 11 * KTSTRIDE + (nt * 64 + lb + 32) * 8;
                #pragma unroll
                for (int jj = 0; jj < 8; ++jj) d1[jj] = 0;
            }
        } else {
            #pragma unroll
            for (int k3 = 0; k3 < 11; ++k3) dst[k3 * KTSTRIDE] = 0;
            if (i == 0) {
                short* d0 = Bg + 11 * KTSTRIDE + (nt * 64 + lb) * 8;
                short* d1 = Bg + 11 * KTSTRIDE + (nt * 64 + lb + 32) * 8;
                #pragma unroll
                for (int jj = 0; jj < 8; ++jj) { d0[jj] = 0; d1[jj] = 0; }
            }
        }
    } else if (g < 2560 + 2048) {
        const int node = g - 2560;
        const float* yr = y + node * 10;
        int e = 0; float best = yr[0];
        #pragma unroll
        for (int s2 = 1; s2 < 10; ++s2) { const float v = yr[s2]; if (v > best) { best = v; e = s2; } }
        ((int*)(Bg + 12 * KTSTRIDE))[node] = e;
    }
}

// ---------------------------------------------------------------------------
// Main (R9 structure): 512-thread block = 8 waves = 2 nodes x 4 ch-groups.
// U (60 KB) staged once into LDS, ONE barrier, then free-running waves:
// 12 kt x {5 ds_read_b128 -> in-reg fp16 B build -> 5 MFMA}. Packed-f32
// register-only epilogue (x reloaded from L1), no further synchronization.
// ---------------------------------------------------------------------------
__global__ __launch_bounds__(512, 4)
void symcon_main(const float* __restrict__ x,
                 const float* __restrict__ U1, const float* __restrict__ W3,
                 const float* __restrict__ W2, const float* __restrict__ W1,
                 const short* __restrict__ Bg, float* __restrict__ out)
{
    __shared__ __align__(16) short Ul[NCHUNK * 8];   // 61440 B

    const int tid  = threadIdx.x;
    const int lane = tid & 63;
    const int wid  = tid >> 6;            // 0..7
    const int node = blockIdx.x * 2 + (wid >> 2);
    const int wr   = wid & 3;
    const int col  = lane & 31;
    const int h    = lane >> 5;
    const int m    = wr * 32 + col;       // channel this lane owns

    // ---- stage U into LDS: 3840 chunks = 60 wave-loads (8 waves x 7 + 4) ----
    #pragma unroll
    for (int jj = 0; jj < 7; ++jj) {
        const int c = ((jj * 8 + wid) << 6) + lane;
        gload16(Bg + c * 8, &Ul[c * 8]);
    }
    if (wid < 4) {
        const int c = ((56 + wid) << 6) + lane;
        gload16(Bg + c * 8, &Ul[c * 8]);
    }

    // ---- species from prep ----
    const int e = ((const int*)(Bg + 12 * KTSTRIDE))[node];

    // ---- lane's x half (i = 8h..8h+7) -> packed fp16 ----
    const float* xp = x + ((size_t)node * 128 + m) * 16;
    h2 xh[4];
    {
        const v4f lo = *reinterpret_cast<const v4f*>(xp + h * 8);
        const v4f hi = *reinterpret_cast<const v4f*>(xp + h * 8 + 4);
        xh[0] = h2{(__fp16)lo[0], (__fp16)lo[1]};
        xh[1] = h2{(__fp16)lo[2], (__fp16)lo[3]};
        xh[2] = h2{(__fp16)hi[0], (__fp16)hi[1]};
        xh[3] = h2{(__fp16)hi[2], (__fp16)hi[3]};
    }

    // ---- per-lane weights (e-dependent gather, coalesced 32-lane rows) ----
    float w3r[11], w2r[4];
    #pragma unroll
    for (int k = 0; k < 11; ++k) w3r[k] = W3[(e * 11 + k) * 128 + m];
    #pragma unroll
    for (int k = 0; k < 4; ++k)  w2r[k] = W2[(e * 4 + k) * 128 + m];
    const float w1v = W1[e * 128 + m];

    __syncthreads();   // U staged (drains vmcnt); the ONLY barrier

    v16f a0 = {}, a1 = {}, a2 = {}, a3 = {}, a4 = {};

    // ---- K loop: 12 kt x 5 n-tiles; A from LDS, B built in-register ----
    const short* Up = Ul + lane * 8;
    #pragma unroll
    for (int kt = 0; kt < 12; ++kt) {
        const v8h u0 = *reinterpret_cast<const v8h*>(Up + (kt * NT + 0) * 512);
        const v8h u1 = *reinterpret_cast<const v8h*>(Up + (kt * NT + 1) * 512);
        const v8h u2 = *reinterpret_cast<const v8h*>(Up + (kt * NT + 2) * 512);
        const v8h u3 = *reinterpret_cast<const v8h*>(Up + (kt * NT + 3) * 512);
        const v8h u4 = *reinterpret_cast<const v8h*>(Up + (kt * NT + 4) * 512);
        v8h b;
        if (kt < 11) {
            const __fp16 w = (__fp16)w3r[kt];
            const h2 wh = h2{w, w};
            b = pack4(xh[0] * wh, xh[1] * wh, xh[2] * wh, xh[3] * wh);
        } else {
            const h2 z = {};
            const h2 p0 = h ? z : h2{(__fp16)w2r[0], (__fp16)w2r[1]};
            const h2 p1 = h ? z : h2{(__fp16)w2r[2], (__fp16)w2r[3]};
            b = pack4(p0, p1, z, z);
        }
        a0 = mfma_f16(u0, b, a0);
        a1 = mfma_f16(u1, b, a1);
        a2 = mfma_f16(u2, b, a2);
        a3 = mfma_f16(u3, b, a3);
        a4 = mfma_f16(u4, b, a4);
    }

    // ---- reload full x row (L1-hot), packed-f32 epilogue + U1 term ----
    const v4f f0 = *reinterpret_cast<const v4f*>(xp);
    const v4f f1 = *reinterpret_cast<const v4f*>(xp + 4);
    const v4f f2 = *reinterpret_cast<const v4f*>(xp + 8);
    const v4f f3 = *reinterpret_cast<const v4f*>(xp + 12);

    v2f s2 = {0.f, 0.f};
    if (h == 0) {
        epi2<0, 0>(s2, a0, f0, f1, f2, f3);
        epi2<1, 0>(s2, a1, f0, f1, f2, f3);
        epi2<2, 0>(s2, a2, f0, f1, f2, f3);
        epi2<3, 0>(s2, a3, f0, f1, f2, f3);
        epi2<4, 0>(s2, a4, f0, f1, f2, f3);
    } else {
        epi2<0, 1>(s2, a0, f0, f1, f2, f3);
        epi2<1, 1>(s2, a1, f0, f1, f2, f3);
        epi2<2, 1>(s2, a2, f0, f1, f2, f3);
        epi2<3, 1>(s2, a3, f0, f1, f2, f3);
        epi2<4, 1>(s2, a4, f0, f1, f2, f3);
    }
    float s = s2[0] + s2[1];

    float u1dot;
    {
        const v4f u0q = *reinterpret_cast<const v4f*>(U1);
        const v4f u1q = *reinterpret_cast<const v4f*>(U1 + 4);
        const v4f u2q = *reinterpret_cast<const v4f*>(U1 + 8);
        const v4f u3q = *reinterpret_cast<const v4f*>(U1 + 12);
        const v4f d = f0 * u0q + f1 * u1q + f2 * u2q + f3 * u3q;
        u1dot = d[0] + d[1] + d[2] + d[3];
    }

    s += __shfl_xor(s, 32);   // combine h=0/h=1 n-halves (same m)

    if (h == 0)
        out[(size_t)node * 128 + m] = s + w1v * u1dot;
}

extern "C" void kernel_launch(void* const* d_in, const int* in_sizes, int n_in,
                              void* d_out, int out_size, void* d_ws, size_t ws_size,
                              hipStream_t stream) {
    const float* x  = (const float*)d_in[0];
    const float* y  = (const float*)d_in[1];
    const float* U3 = (const float*)d_in[2];
    const float* U2 = (const float*)d_in[3];
    const float* U1 = (const float*)d_in[4];
    const float* W3 = (const float*)d_in[5];
    const float* W2 = (const float*)d_in[6];
    const float* W1 = (const float*)d_in[7];
    short* Bg = (short*)d_ws;   // 60 KB fp16 Usym + 8 KB e[]

    symcon_prep<<<18, 256, 0, stream>>>(U3, U2, y, Bg);
    symcon_main<<<1024, 512, 0, stream>>>(x, U1, W3, W2, W1, Bg, (float*)d_out);
}